// Round 8
// baseline (58.486 us; speedup 1.0000x reference)
//
#include <hip/hip_runtime.h>

// Locally-connected 2d: x[32,16,66,66], w[1,32,16,64,64,9], bias[1,32,64,64]
// out[32,32,64,64] fp32.
//
// R8: full pre-pack design. Per (h,w): out[b,o] = sum_{c,k} X W = GEMM 32x32x144.
// kflat = kappa*16 + c  ->  MFMA m == kernel position kappa=m (9 MFMAs, no pad).
// d_ws: xP[hh][ww][b][c] bf16 (4.46 MB), Wp[h][w][kappa][o][c] bf16 (37.7 MB).
// Both A and B fragments = one coalesced dwordx4 per MFMA (1KB tile per wave).
// Main: 9x(2 loads + MFMA) + LDS-transpose epilogue (float4 stores).
// prep_w: coalesced single-pass reads, scattered dwordx4 writes.
// Fallback: R7 verified kernels if ws too small.

#define CI_ 16
#define H_  64
#define W_  64
#define XW_ 66

typedef float f32x16 __attribute__((ext_vector_type(16)));
typedef short s16x8  __attribute__((ext_vector_type(8)));

__device__ inline short f2bf(float f) {  // RNE float->bf16
  unsigned u = __builtin_bit_cast(unsigned, f);
  u += 0x7fffu + ((u >> 16) & 1u);
  return (short)(u >> 16);
}

// ---- prep_x: x[b][c][hh][ww] f32 -> xP[hh][ww][b][c] bf16 -------------------
// thread = (hh,ww,b,c-octet): 8 gathered reads (stride 4356), 1 dwordx4 write.
__global__ __launch_bounds__(256) void prep_x(const float* __restrict__ x,
                                              short* __restrict__ xP) {
  const int t = blockIdx.x * 256 + threadIdx.x;  // 66*66*32*2 = 278784 exact
  const int oct = t & 1;
  const int b   = (t >> 1) & 31;
  const int hhww = t >> 6;                       // hh*66+ww
  const float* sp = x + ((size_t)b * CI_ + oct * 8) * 4356 + hhww;
  s16x8 v;
#pragma unroll
  for (int e = 0; e < 8; ++e) v[e] = f2bf(sp[(size_t)e * 4356]);
  *(s16x8*)(xP + (size_t)t * 8) = v;
}

// ---- prep_w: wt[o][c][h][w][k] f32 -> Wp[h][w][k][o][c] bf16 ----------------
// wave = (o,oct, hwk-chunk): lanes cover 64 consecutive hwk -> reads fully
// coalesced, every float read exactly once. Writes: scattered dwordx4.
__global__ __launch_bounds__(256) void prep_w(const float* __restrict__ wt,
                                              short* __restrict__ Wp) {
  const int tx = threadIdx.x;
  const int widx = tx >> 6, lane = tx & 63;
  const int Wv = blockIdx.x * 4 + widx;          // 9216*4 = 36864 waves
  const int og    = Wv / 576;                    // o*2+oct
  const int hwblk = Wv - og * 576;
  const int hwk = hwblk * 64 + lane;             // (h*64+w)*9+kappa, < 36864
  const int o = og >> 1, oct = og & 1;
  const float* sp = wt + (size_t)(o * CI_ + oct * 8) * 36864 + hwk;
  s16x8 v;
#pragma unroll
  for (int e = 0; e < 8; ++e) v[e] = f2bf(sp[(size_t)e * 36864]);
  *(s16x8*)(Wp + ((size_t)hwk * 32 + o) * 16 + oct * 8) = v;
}

// ---- main: wave per (h,w); 9 MFMAs; LDS-transpose epilogue ------------------
__global__ __launch_bounds__(256) void lc2d_main(const short* __restrict__ xP,
                                                 const short* __restrict__ Wp,
                                                 const float* __restrict__ bias,
                                                 float* __restrict__ out) {
  __shared__ float tr[4 * 32 * 32];  // [w2][b][o] f32, 16 KB

  const int d = blockIdx.x;                      // 1024 blocks, XCD-bijective
  const int L = (d & 7) * 128 + (d >> 3);
  const int wq = L & 15;
  const int h  = L >> 4;
  const int tx = threadIdx.x;                    // 0..63
  const int w2 = threadIdx.y;                    // 0..3 (wave id)
  const int ln = tx & 31;                        // A-row (b) / B-col (o)
  const int half = tx >> 5;                      // k-half: c = half*8+e
  const int w = wq * 4 + w2;

  f32x16 acc = {0,0,0,0,0,0,0,0,0,0,0,0,0,0,0,0};
  const short* ap0 = xP + ln * 16 + half * 8;
  const short* bp  = Wp + ((size_t)(h * W_ + w) * 9 * 32 + ln) * 16 + half * 8;

#pragma unroll
  for (int kk = 0; kk < 9; ++kk) {
    const int i = kk / 3, j = kk - 3 * i;
    const s16x8 af = *(const s16x8*)(ap0 + (size_t)((h + i) * XW_ + (w + j)) * 512);
    const s16x8 bf = *(const s16x8*)(bp + (size_t)kk * 512);
    acc = __builtin_amdgcn_mfma_f32_32x32x16_bf16(af, bf, acc, 0, 0, 0);
  }

  // C/D layout: col(o)=lane&31, row(b)=(r&3)+8*(r>>2)+4*half (verified R7).
#pragma unroll
  for (int r = 0; r < 16; ++r) {
    const int b = (r & 3) + 8 * (r >> 2) + 4 * half;
    tr[(w2 * 32 + b) * 32 + ln] = acc[r];
  }
  __syncthreads();

  const int tid = w2 * 64 + tx;                  // 0..255
  const int o = tid & 31;
  const int brow = tid >> 5;                     // 0..7
  const float4 bv = *(const float4*)(bias + ((size_t)o * H_ + h) * W_ + wq * 4);
#pragma unroll
  for (int it = 0; it < 4; ++it) {
    const int b = it * 8 + brow;
    float4 v;
    v.x = tr[(0 * 32 + b) * 32 + o] + bv.x;
    v.y = tr[(1 * 32 + b) * 32 + o] + bv.y;
    v.z = tr[(2 * 32 + b) * 32 + o] + bv.z;
    v.w = tr[(3 * 32 + b) * 32 + o] + bv.w;
    *(float4*)(out + ((size_t)b * 32 + o) * (H_ * W_) + h * W_ + wq * 4) = v;
  }
}

// ======================= R7 fallback (verified) ==============================
__global__ __launch_bounds__(256) void transpose_x(const float* __restrict__ x,
                                                   float* __restrict__ xT) {
  const int idx = blockIdx.x * 256 + threadIdx.x;
  const int ww = idx % 66;
  int t = idx / 66;
  const int hh = t % 66; t /= 66;
  const int c = t % 16;
  const int b = t / 16;
  xT[(((size_t)c * 66 + hh) * 66 + ww) * 32 + b] = x[idx];
}

template <int TRANS>
__global__ __launch_bounds__(256, 4) void lc2d_mfma(
    const float* __restrict__ xs, const float* __restrict__ wt,
    const float* __restrict__ bias, float* __restrict__ out) {
  __shared__ float wlds[8 * 32 * 36];
  const int d = blockIdx.x;
  const int L = (d & 7) * 128 + (d >> 3);
  const int wq = L & 15;
  const int h  = L >> 4;
  const int tx = threadIdx.x;
  const int w2 = threadIdx.y;
  const int ln = tx & 31;
  const int half = tx >> 5;
  const int tid = w2 * 64 + tx;
  const int w = wq * 4 + w2;
  f32x16 acc = {0,0,0,0,0,0,0,0,0,0,0,0,0,0,0,0};
  const int bbase = ln * 36 + w2 * 9;
  size_t abase;
  if (TRANS) abase = (((size_t)h) * XW_ + w) * 32 + ln;
  else       abase = (size_t)ln * 69696 + (size_t)h * XW_ + w;

  for (int s = 0; s < 2; ++s) {
    const int c0 = s * 8;
    __syncthreads();
#pragma unroll
    for (int i = 0; i < 9; ++i) {
      const int f4 = tid + i * 256;
      const int cc = f4 / 288;
      const int rem = f4 - cc * 288;
      const int oo = rem / 9;
      const int q = rem - oo * 9;
      const float4* src = (const float4*)wt +
          (((size_t)oo * CI_ + (c0 + cc)) * H_ + h) * 144 + (size_t)wq * 9 + q;
      ((float4*)wlds)[f4] = *src;
    }
    __syncthreads();
#pragma unroll
    for (int cc = 0; cc < 8; ++cc) {
      const int c = c0 + cc;
      const float* ap = xs + abase + (size_t)c * (TRANS ? 139392 : 4356);
      float av[8] = {0,0,0,0,0,0,0,0};
      float bvv[8] = {0,0,0,0,0,0,0,0};
      av[0] = ap[half ? (TRANS ? (2 * XW_ + 2) * 32 : (2 * XW_ + 2)) : 0];
      bvv[0] = wlds[cc * 1152 + bbase + (half ? 8 : 0)];
      if (half == 0) {
#pragma unroll
        for (int e = 1; e < 8; ++e) {
          const int i = e / 3, j = e - 3 * i;
          av[e] = ap[(i * XW_ + j) * (TRANS ? 32 : 1)];
          bvv[e] = wlds[cc * 1152 + bbase + e];
        }
      }
      s16x8 af, bf;
#pragma unroll
      for (int e = 0; e < 8; ++e) { af[e] = f2bf(av[e]); bf[e] = f2bf(bvv[e]); }
      acc = __builtin_amdgcn_mfma_f32_32x32x16_bf16(af, bf, acc, 0, 0, 0);
    }
  }
  const float bvv = bias[((size_t)ln * H_ + h) * W_ + w];
#pragma unroll
  for (int r = 0; r < 16; ++r) {
    const int b = (r & 3) + 8 * (r >> 2) + 4 * half;
    out[(((size_t)b * 32 + ln) * H_ + h) * W_ + w] = acc[r] + bvv;
  }
}

extern "C" void kernel_launch(void* const* d_in, const int* in_sizes, int n_in,
                              void* d_out, int out_size, void* d_ws, size_t ws_size,
                              hipStream_t stream) {
  const float* x    = (const float*)d_in[0];
  const float* wt   = (const float*)d_in[1];
  const float* bias = (const float*)d_in[2];
  float* out = (float*)d_out;

  const size_t xp_elems = (size_t)66 * 66 * 32 * 16;        // 2,230,272 shorts
  const size_t wp_elems = (size_t)H_ * W_ * 9 * 32 * 16;    // 18,874,368 shorts
  const size_t need = (xp_elems + wp_elems) * sizeof(short); // 42,209,280 B

  dim3 block(64, 4, 1);
  if (ws_size >= need) {
    short* xP = (short*)d_ws;
    short* Wp = xP + xp_elems;
    prep_x<<<1089, 256, 0, stream>>>(x, xP);
    prep_w<<<9216, 256, 0, stream>>>(wt, Wp);
    lc2d_main<<<1024, block, 0, stream>>>(xP, Wp, bias, out);
  } else if (ws_size >= (size_t)CI_ * 66 * 66 * 32 * sizeof(float)) {
    float* xT = (float*)d_ws;
    transpose_x<<<8712, 256, 0, stream>>>(x, xT);
    lc2d_mfma<1><<<1024, block, 0, stream>>>(xT, wt, bias, out);
  } else {
    lc2d_mfma<0><<<1024, block, 0, stream>>>(x, wt, bias, out);
  }
}

// Round 9
// 40.175 us; speedup vs baseline: 1.4558x; 1.4558x over previous
//
#include <hip/hip_runtime.h>

// Locally-connected 2d: x[32,16,66,66], w[1,32,16,64,64,9], bias[1,32,64,64]
// out[32,32,64,64] fp32.
//
// R9: fused weight repack. Per (h,w): out[b,o] = GEMM 32x32x144, kflat = kappa*16+c
// -> 9 MFMAs (32x32x16 bf16), no K padding. Block = (h, w-quad), 4 waves.
//  - weights: block reads its disjoint 72KB slice coalesced (144-B chunks, each
//    float exactly once grid-wide), converts bf16, scatters into LDS tile
//    pw[w2][kappa][o][c] with 16B-granule XOR swizzle g ^= (o^kappa)&7
//    (bijective; ds_read_b128 = 2 lanes/bank = free; writes ~2-way).
//  - x: prep_x packs xP[hh][ww][b][c] bf16 (4.5 MB in d_ws); A-fragments are
//    coalesced dwordx4 (1KB/wave).
//  - epilogue: LDS transpose (reusing pw) + float4 stores.
// HBM ~110 MB (~17.5 us floor) vs R8's ~151 MB weight path + extra dispatch.

#define CI_ 16
#define H_  64
#define W_  64
#define XW_ 66

typedef float f32x16 __attribute__((ext_vector_type(16)));
typedef short s16x8  __attribute__((ext_vector_type(8)));

__device__ inline short f2bf(float f) {  // RNE float->bf16
  unsigned u = __builtin_bit_cast(unsigned, f);
  u += 0x7fffu + ((u >> 16) & 1u);
  return (short)(u >> 16);
}

// ---- prep_x: x[b][c][hh][ww] f32 -> xP[hh][ww][b][c] bf16 (verified R8) ----
__global__ __launch_bounds__(256) void prep_x(const float* __restrict__ x,
                                              short* __restrict__ xP) {
  const int t = blockIdx.x * 256 + threadIdx.x;  // 66*66*32*2 = 278784 exact
  const int oct = t & 1;
  const int b   = (t >> 1) & 31;
  const int hhww = t >> 6;
  const float* sp = x + ((size_t)b * CI_ + oct * 8) * 4356 + hhww;
  s16x8 v;
#pragma unroll
  for (int e = 0; e < 8; ++e) v[e] = f2bf(sp[(size_t)e * 4356]);
  *(s16x8*)(xP + (size_t)t * 8) = v;
}

// ---- fused main: stage weights -> LDS packed+swizzled; 9 MFMAs; transpose ----
__global__ __launch_bounds__(256, 4) void lc2d_fused(
    const short* __restrict__ xP, const float* __restrict__ wt,
    const float* __restrict__ bias, float* __restrict__ out) {
  __shared__ short pw[4 * 9 * 32 * 16];  // 18432 shorts = 36 KB (also epilogue tr)

  const int d = blockIdx.x;                      // 1024 blocks, XCD-bijective
  const int L = (d & 7) * 128 + (d >> 3);
  const int wq = L & 15;
  const int h  = L >> 4;
  const int tx = threadIdx.x;                    // 0..63
  const int w2 = threadIdx.y;                    // 0..3 (wave id = w within quad)
  const int tid = w2 * 64 + tx;

  // Stage: 512 (o,c) segs x 9 float4 (36 floats: w2f 0..3 x kappa 0..8).
  // Source chunk per seg: 144 B contiguous, 16B aligned. 18 float4 per thread.
#pragma unroll
  for (int i = 0; i < 18; ++i) {
    const int f4 = tid + i * 256;                // 0..4607
    const int seg = f4 / 9;                      // o*16 + c
    const int q   = f4 - seg * 9;
    const int o = seg >> 4, c = seg & 15;
    const float4 v = ((const float4*)wt)[((size_t)seg * H_ + h) * 144 + wq * 9 + q];
    const float* vv = (const float*)&v;
#pragma unroll
    for (int e = 0; e < 4; ++e) {
      const int flat = 4 * q + e;                // 0..35
      const int w2f = flat / 9;
      const int k   = flat - w2f * 9;
      const int idx = ((w2f * 9 + k) * 32 + o) * 16 + c;
      const int g   = (idx >> 3) ^ ((o ^ k) & 7);    // 16B-granule swizzle
      pw[(g << 3) | (idx & 7)] = f2bf(vv[e]);
    }
  }
  __syncthreads();

  const int ln   = tx & 31;                      // A-row (b) / B-col (o)
  const int half = tx >> 5;                      // c-half: c = half*8 + e
  const int w = wq * 4 + w2;

  f32x16 acc = {0,0,0,0,0,0,0,0,0,0,0,0,0,0,0,0};
  const short* ap0 = xP + ln * 16 + half * 8;
#pragma unroll
  for (int kk = 0; kk < 9; ++kk) {
    const int i = kk / 3, j = kk - 3 * i;
    const s16x8 af = *(const s16x8*)(ap0 + (size_t)((h + i) * XW_ + (w + j)) * 512);
    int g = ((w2 * 9 + kk) * 32 + ln) * 2 + half;
    g ^= (ln ^ kk) & 7;
    const s16x8 bf = *(const s16x8*)(pw + (g << 3));
    acc = __builtin_amdgcn_mfma_f32_32x32x16_bf16(af, bf, acc, 0, 0, 0);
  }

  // Epilogue: C/D layout col(o)=ln, row(b)=(r&3)+8*(r>>2)+4*half (verified).
  __syncthreads();                               // all ds_reads of pw done
  float* tr = (float*)pw;                        // 16 KB reuse
#pragma unroll
  for (int r = 0; r < 16; ++r) {
    const int b = (r & 3) + 8 * (r >> 2) + 4 * half;
    tr[(w2 * 32 + b) * 32 + ln] = acc[r];
  }
  __syncthreads();

  const int o = tid & 31;
  const int brow = tid >> 5;                     // 0..7
  const float4 bv = *(const float4*)(bias + ((size_t)o * H_ + h) * W_ + wq * 4);
#pragma unroll
  for (int it = 0; it < 4; ++it) {
    const int b = it * 8 + brow;
    float4 v;
    v.x = tr[(0 * 32 + b) * 32 + o] + bv.x;
    v.y = tr[(1 * 32 + b) * 32 + o] + bv.y;
    v.z = tr[(2 * 32 + b) * 32 + o] + bv.z;
    v.w = tr[(3 * 32 + b) * 32 + o] + bv.w;
    *(float4*)(out + ((size_t)b * 32 + o) * (H_ * W_) + h * W_ + wq * 4) = v;
  }
}

// ---- fallback (R7-verified, no workspace): gather MFMA ----------------------
__global__ __launch_bounds__(256, 4) void lc2d_mfma0(
    const float* __restrict__ xs, const float* __restrict__ wt,
    const float* __restrict__ bias, float* __restrict__ out) {
  __shared__ float wlds[8 * 32 * 36];
  const int d = blockIdx.x;
  const int L = (d & 7) * 128 + (d >> 3);
  const int wq = L & 15;
  const int h  = L >> 4;
  const int tx = threadIdx.x;
  const int w2 = threadIdx.y;
  const int ln = tx & 31;
  const int half = tx >> 5;
  const int tid = w2 * 64 + tx;
  const int w = wq * 4 + w2;
  f32x16 acc = {0,0,0,0,0,0,0,0,0,0,0,0,0,0,0,0};
  const int bbase = ln * 36 + w2 * 9;
  size_t abase = (size_t)ln * 69696 + (size_t)h * XW_ + w;

  for (int s = 0; s < 2; ++s) {
    const int c0 = s * 8;
    __syncthreads();
#pragma unroll
    for (int i = 0; i < 9; ++i) {
      const int f4 = tid + i * 256;
      const int cc = f4 / 288;
      const int rem = f4 - cc * 288;
      const int oo = rem / 9;
      const int q = rem - oo * 9;
      const float4* src = (const float4*)wt +
          (((size_t)oo * CI_ + (c0 + cc)) * H_ + h) * 144 + (size_t)wq * 9 + q;
      ((float4*)wlds)[f4] = *src;
    }
    __syncthreads();
#pragma unroll
    for (int cc = 0; cc < 8; ++cc) {
      const int c = c0 + cc;
      const float* ap = xs + abase + (size_t)c * 4356;
      float av[8] = {0,0,0,0,0,0,0,0};
      float bvv[8] = {0,0,0,0,0,0,0,0};
      av[0] = ap[half ? (2 * XW_ + 2) : 0];
      bvv[0] = wlds[cc * 1152 + bbase + (half ? 8 : 0)];
      if (half == 0) {
#pragma unroll
        for (int e = 1; e < 8; ++e) {
          const int i = e / 3, j = e - 3 * i;
          av[e] = ap[i * XW_ + j];
          bvv[e] = wlds[cc * 1152 + bbase + e];
        }
      }
      s16x8 af, bf;
#pragma unroll
      for (int e = 0; e < 8; ++e) { af[e] = f2bf(av[e]); bf[e] = f2bf(bvv[e]); }
      acc = __builtin_amdgcn_mfma_f32_32x32x16_bf16(af, bf, acc, 0, 0, 0);
    }
  }
  const float bvv = bias[((size_t)ln * H_ + h) * W_ + w];
#pragma unroll
  for (int r = 0; r < 16; ++r) {
    const int b = (r & 3) + 8 * (r >> 2) + 4 * half;
    out[(((size_t)b * 32 + ln) * H_ + h) * W_ + w] = acc[r] + bvv;
  }
}

extern "C" void kernel_launch(void* const* d_in, const int* in_sizes, int n_in,
                              void* d_out, int out_size, void* d_ws, size_t ws_size,
                              hipStream_t stream) {
  const float* x    = (const float*)d_in[0];
  const float* wt   = (const float*)d_in[1];
  const float* bias = (const float*)d_in[2];
  float* out = (float*)d_out;

  const size_t xp_bytes = (size_t)66 * 66 * 32 * 16 * sizeof(short);  // 4.46 MB
  dim3 block(64, 4, 1);
  if (ws_size >= xp_bytes) {
    short* xP = (short*)d_ws;
    prep_x<<<1089, 256, 0, stream>>>(x, xP);
    lc2d_fused<<<1024, block, 0, stream>>>(xP, wt, bias, out);
  } else {
    lc2d_mfma0<<<1024, block, 0, stream>>>(x, wt, bias, out);
  }
}